// Round 2
// baseline (398.934 us; speedup 1.0000x reference)
//
#include <hip/hip_runtime.h>

// B=128, S=1024, H=256
#define Bb 128
#define Ss 1024
#define Hh 256
#define NEGF 1e9f

typedef short bf16x8 __attribute__((ext_vector_type(8)));
typedef float f32x4 __attribute__((ext_vector_type(4)));

__device__ __forceinline__ short f2bf(float f) {
    union { float f; unsigned u; } c; c.f = f;
    return (short)((c.u + 0x8000u) >> 16);
}

__device__ __forceinline__ bf16x8 ld_bf8_f32(const float* p) {
    // p must be 16B aligned; loads 8 consecutive floats, converts to bf16
    const float4* p4 = (const float4*)p;
    float4 a = p4[0], b = p4[1];
    bf16x8 r;
    r[0] = f2bf(a.x); r[1] = f2bf(a.y); r[2] = f2bf(a.z); r[3] = f2bf(a.w);
    r[4] = f2bf(b.x); r[5] = f2bf(b.y); r[6] = f2bf(b.z); r[7] = f2bf(b.w);
    return r;
}

__device__ __forceinline__ float fast_tanh(float x) {
    float cl = fminf(fmaxf(x, -10.f), 10.f);
    float e = __expf(2.f * cl);
    return (e - 1.f) * __builtin_amdgcn_rcpf(e + 1.f);
}

// ---------------- K0a: convert wg, wp (fp32 [H,H]) -> bf16 in ws ----------------
__global__ __launch_bounds__(256) void convert_w(const float* __restrict__ wg,
                                                 const float* __restrict__ wp,
                                                 short* __restrict__ wgb,
                                                 short* __restrict__ wpb) {
    int i = blockIdx.x * 256 + threadIdx.x;   // grid 256 -> 65536 threads
    wgb[i] = f2bf(wg[i]);
    wpb[i] = f2bf(wp[i]);
}

// ---------------- K0b / small GEMV: out[b,h] = sum_d q[b,d]*W[h,d] + bias[h] ----
__global__ __launch_bounds__(256) void dot_qb(const float* __restrict__ q,
                                              const float* __restrict__ W,
                                              const float* __restrict__ bias,
                                              float* __restrict__ out) {
    int b = blockIdx.x, h = threadIdx.x;
    const float4* qr = (const float4*)(q + b * Hh);
    const float4* wr = (const float4*)(W + h * Hh);
    float acc = 0.f;
#pragma unroll 8
    for (int i = 0; i < Hh / 4; ++i) {
        float4 q4 = qr[i], w4 = wr[i];
        acc += q4.x * w4.x + q4.y * w4.y + q4.z * w4.z + q4.w * w4.w;
    }
    out[b * Hh + h] = acc + bias[h];
}

// ---------------- Main fused GEMM: scores[b,s] = sum_h tanh((ref@W^T)[s,h]+qbias[b,h])*v[h]
// grid (B, S/128), block 256 = 4 waves; each wave: 32 rows (2 MFMA m-tiles)
template <int MASKED>
__global__ __launch_bounds__(256) void scores_mfma(const float* __restrict__ ref,
                                                   const short* __restrict__ Wbf,
                                                   const float* __restrict__ qbias,
                                                   const float* __restrict__ vvec,
                                                   const int* __restrict__ mask,
                                                   float* __restrict__ out) {
    const int b = blockIdx.x;
    const int s0 = blockIdx.y * 128;
    const int wave = threadIdx.x >> 6;
    const int lane = threadIdx.x & 63;
    const int nl = lane & 15;
    const int quad = lane >> 4;
    const int rowbase = s0 + wave * 32;

    // A fragments: A[m=lane&15][k=quad*8+j], k-step 32 per MFMA
    bf16x8 afrag[2][8];
#pragma unroll
    for (int rt = 0; rt < 2; ++rt) {
        const float* rp = ref + ((size_t)b * Ss + rowbase + rt * 16 + nl) * Hh;
#pragma unroll
        for (int kb = 0; kb < 8; ++kb)
            afrag[rt][kb] = ld_bf8_f32(rp + kb * 32 + quad * 8);
    }

    float sc[2][4] = {{0.f, 0.f, 0.f, 0.f}, {0.f, 0.f, 0.f, 0.f}};

    for (int nc = 0; nc < 16; ++nc) {
        const int n = nc * 16 + nl;
        const short* wr = Wbf + n * Hh;
        bf16x8 bfrag[8];
#pragma unroll
        for (int kb = 0; kb < 8; ++kb)
            bfrag[kb] = *(const bf16x8*)(wr + kb * 32 + quad * 8);
        const float qb = qbias[b * Hh + n];
        const float vv = vvec[n];
#pragma unroll
        for (int rt = 0; rt < 2; ++rt) {
            f32x4 c = {0.f, 0.f, 0.f, 0.f};
#pragma unroll
            for (int kb = 0; kb < 8; ++kb)
                c = __builtin_amdgcn_mfma_f32_16x16x32_bf16(afrag[rt][kb], bfrag[kb], c, 0, 0, 0);
            // C/D layout: col = lane&15 (= n), row = quad*4 + r
#pragma unroll
            for (int r = 0; r < 4; ++r)
                sc[rt][r] += fast_tanh(c[r] + qb) * vv;
        }
    }

    // reduce over n (the 16 lanes within a quad)
#pragma unroll
    for (int rt = 0; rt < 2; ++rt)
#pragma unroll
        for (int r = 0; r < 4; ++r) {
            float v = sc[rt][r];
            v += __shfl_xor(v, 1, 64);
            v += __shfl_xor(v, 2, 64);
            v += __shfl_xor(v, 4, 64);
            v += __shfl_xor(v, 8, 64);
            sc[rt][r] = v;
        }

    if (nl == 0) {
#pragma unroll
        for (int rt = 0; rt < 2; ++rt)
#pragma unroll
            for (int r = 0; r < 4; ++r) {
                int m = rowbase + rt * 16 + quad * 4 + r;
                float v = sc[rt][r];
                if (MASKED) v -= (float)mask[b * Ss + m] * NEGF;
                out[(size_t)b * Ss + m] = v;
            }
    }
}

// ---------------- Softmax over S per batch (mask applied) -> att ----------------
__global__ __launch_bounds__(1024) void softmax_kernel(const float* __restrict__ scores,
                                                       const int* __restrict__ mask,
                                                       float* __restrict__ att) {
    int b = blockIdx.x, t = threadIdx.x;
    __shared__ float red[16];
    int idx = b * Ss + t;
    float x = scores[idx] - (float)mask[idx] * NEGF;

    float m = x;
#pragma unroll
    for (int o = 1; o < 64; o <<= 1) m = fmaxf(m, __shfl_xor(m, o, 64));
    if ((t & 63) == 0) red[t >> 6] = m;
    __syncthreads();
    float M = red[0];
#pragma unroll
    for (int j = 1; j < 16; ++j) M = fmaxf(M, red[j]);
    __syncthreads();

    float e = __expf(x - M);
    float s = e;
#pragma unroll
    for (int o = 1; o < 64; o <<= 1) s += __shfl_xor(s, o, 64);
    if ((t & 63) == 0) red[t >> 6] = s;
    __syncthreads();
    float S = 0.f;
#pragma unroll
    for (int j = 0; j < 16; ++j) S += red[j];

    att[idx] = e * __builtin_amdgcn_rcpf(S);
}

// ---------------- Glimpse partial: gpart[b,q,d] = sum_{s in quarter q} att[b,s]*ref[b,s,d]
__global__ __launch_bounds__(256) void glimpse_part(const float* __restrict__ ref,
                                                    const float* __restrict__ att,
                                                    float* __restrict__ gpart) {
    int b = blockIdx.x, q = blockIdx.y, d = threadIdx.x;
    const float* rp = ref + ((size_t)b * Ss + q * 256) * Hh + d;
    const float* ap = att + b * Ss + q * 256;
    float acc = 0.f;
#pragma unroll 8
    for (int s = 0; s < 256; ++s) acc += ap[s] * rp[(size_t)s * Hh];
    gpart[(b * 4 + q) * Hh + d] = acc;
}

// ---------------- qbias_p[b,h] = sum_d (glimpse)[b,d]*wqp[h,d] + bp[h] ----------
__global__ __launch_bounds__(256) void qbias_p_kernel(const float* __restrict__ gpart,
                                                      const float* __restrict__ query,
                                                      const float* __restrict__ wqp,
                                                      const float* __restrict__ bp,
                                                      float* __restrict__ out) {
    int b = blockIdx.x, t = threadIdx.x;
    __shared__ __align__(16) float gl[Hh];
    float g = gpart[(b * 4 + 0) * Hh + t] + gpart[(b * 4 + 1) * Hh + t] +
              gpart[(b * 4 + 2) * Hh + t] + gpart[(b * 4 + 3) * Hh + t] +
              query[b * Hh + t];
    gl[t] = g;
    __syncthreads();
    const float4* wr = (const float4*)(wqp + t * Hh);
    const float4* gp = (const float4*)gl;
    float acc = 0.f;
#pragma unroll 8
    for (int i = 0; i < Hh / 4; ++i) {
        float4 w4 = wr[i];
        float4 g4 = gp[i];
        acc += w4.x * g4.x + w4.y * g4.y + w4.z * g4.z + w4.w * g4.w;
    }
    out[b * Hh + t] = acc + bp[t];
}

extern "C" void kernel_launch(void* const* d_in, const int* in_sizes, int n_in,
                              void* d_out, int out_size, void* d_ws, size_t ws_size,
                              hipStream_t stream) {
    const float* ref   = (const float*)d_in[0];
    const float* query = (const float*)d_in[1];
    const int*   mask  = (const int*)d_in[2];
    const float* wg    = (const float*)d_in[3];
    const float* bg    = (const float*)d_in[4];
    const float* wqg   = (const float*)d_in[5];
    const float* vg    = (const float*)d_in[6];
    const float* wp    = (const float*)d_in[7];
    const float* bp    = (const float*)d_in[8];
    const float* wqp   = (const float*)d_in[9];
    const float* vp    = (const float*)d_in[10];
    float* out = (float*)d_out;

    char* ws = (char*)d_ws;
    short* wg_bf    = (short*)(ws + 0);        // 131072 B
    short* wp_bf    = (short*)(ws + 131072);   // 131072 B
    float* qbias_g  = (float*)(ws + 262144);   // 131072 B
    float* qbias_p  = (float*)(ws + 393216);   // 131072 B
    float* scores_g = (float*)(ws + 524288);   // 524288 B
    float* att      = (float*)(ws + 1048576);  // 524288 B
    float* gpart    = (float*)(ws + 1572864);  // 524288 B  (total 2 MB)

    convert_w<<<Hh * Hh / 256, 256, 0, stream>>>(wg, wp, wg_bf, wp_bf);
    dot_qb<<<Bb, Hh, 0, stream>>>(query, wqg, bg, qbias_g);
    scores_mfma<0><<<dim3(Bb, Ss / 128), 256, 0, stream>>>(ref, wg_bf, qbias_g, vg, nullptr, scores_g);
    softmax_kernel<<<Bb, Ss, 0, stream>>>(scores_g, mask, att);
    glimpse_part<<<dim3(Bb, 4), 256, 0, stream>>>(ref, att, gpart);
    qbias_p_kernel<<<Bb, Hh, 0, stream>>>(gpart, query, wqp, bp, qbias_p);
    scores_mfma<1><<<dim3(Bb, Ss / 128), 256, 0, stream>>>(ref, wp_bf, qbias_p, vp, mask, out);
}

// Round 3
// 313.158 us; speedup vs baseline: 1.2739x; 1.2739x over previous
//
#include <hip/hip_runtime.h>

// B=128, S=1024, H=256
#define Bb 128
#define Ss 1024
#define Hh 256
#define NEGF 1e9f

typedef short bf16x8 __attribute__((ext_vector_type(8)));
typedef float f32x4 __attribute__((ext_vector_type(4)));

__device__ __forceinline__ short f2bf(float f) {
    union { float f; unsigned u; } c; c.f = f;
    return (short)((c.u + 0x8000u) >> 16);
}

__device__ __forceinline__ bf16x8 ld_bf8_f32(const float* p) {
    const float4* p4 = (const float4*)p;
    float4 a = p4[0], b = p4[1];
    bf16x8 r;
    r[0] = f2bf(a.x); r[1] = f2bf(a.y); r[2] = f2bf(a.z); r[3] = f2bf(a.w);
    r[4] = f2bf(b.x); r[5] = f2bf(b.y); r[6] = f2bf(b.z); r[7] = f2bf(b.w);
    return r;
}

__device__ __forceinline__ float fast_tanh(float x) {
    float cl = fminf(fmaxf(x, -10.f), 10.f);
    float e = __expf(2.f * cl);
    return (e - 1.f) * __builtin_amdgcn_rcpf(e + 1.f);
}

// async global->LDS, 16B per lane; dest = (wave-uniform) lds base + lane*16
__device__ __forceinline__ void stage16(const short* g, short* l) {
    __builtin_amdgcn_global_load_lds((const __attribute__((address_space(1))) void*)g,
                                     (__attribute__((address_space(3))) void*)l, 16, 0, 0);
}

// ---------------- K0a: convert wg, wp (fp32 [H,H]) -> bf16 in ws ----------------
__global__ __launch_bounds__(256) void convert_w(const float* __restrict__ wg,
                                                 const float* __restrict__ wp,
                                                 short* __restrict__ wgb,
                                                 short* __restrict__ wpb) {
    int i = blockIdx.x * 256 + threadIdx.x;
    wgb[i] = f2bf(wg[i]);
    wpb[i] = f2bf(wp[i]);
}

// ---------------- small GEMV: out[b,h] = sum_d q[b,d]*W[h,d] + bias[h] ----------
__global__ __launch_bounds__(256) void dot_qb(const float* __restrict__ q,
                                              const float* __restrict__ W,
                                              const float* __restrict__ bias,
                                              float* __restrict__ out) {
    int b = blockIdx.x, h = threadIdx.x;
    const float4* qr = (const float4*)(q + b * Hh);
    const float4* wr = (const float4*)(W + h * Hh);
    float acc = 0.f;
#pragma unroll 8
    for (int i = 0; i < Hh / 4; ++i) {
        float4 q4 = qr[i], w4 = wr[i];
        acc += q4.x * w4.x + q4.y * w4.y + q4.z * w4.z + q4.w * w4.w;
    }
    out[b * Hh + h] = acc + bias[h];
}

// ---------------- Main fused GEMM: scores[b,s] = sum_n tanh((ref@W^T)[s,n]+qbias[b,n])*v[n]
// grid (B, S/128), block 256 = 4 waves; wave: 32 rows (2 m-tiles), all 256 n.
// W staged block-wide into LDS in 16-row chunks (8 KB), double-buffered via
// global_load_lds; LDS layout is "fragment order": line kb (1 KB) holds lane L's
// 16B B-fragment at offset L*16, so ds_read_b128 is lane-linear (conflict-free).
template <int MASKED>
__global__ __launch_bounds__(256) void scores_mfma(const float* __restrict__ ref,
                                                   const short* __restrict__ Wbf,
                                                   const float* __restrict__ qbias,
                                                   const float* __restrict__ vvec,
                                                   const int* __restrict__ mask,
                                                   float* __restrict__ out) {
    __shared__ short Wlds[2][4096];   // 2 x 8 KB
    const int b = blockIdx.x;
    const int s0 = blockIdx.y * 128;
    const int t = threadIdx.x;
    const int wave = t >> 6;
    const int lane = t & 63;
    const int nl = lane & 15;
    const int quad = lane >> 4;
    const int rowbase = s0 + wave * 32;

    // Staging: thread t=(w*64+l) sources W[chunk + (l&15)][ (w+0/4)*32 + (l>>4)*8 .. +8 ]
    // so that the implicit dest (wave line kb=w / kb=w+4, offset l*16) holds exactly
    // the fragment read-lane l needs.
    const int soff0 = (t & 15) * Hh + (t >> 6) * 32 + ((t >> 4) & 3) * 8;  // shorts
    const int soff1 = soff0 + 128;                                         // kb+4
    const int dbase0 = wave * 512;          // shorts (byte wave*1024)
    const int dbase1 = 2048 + wave * 512;   // shorts (byte 4096 + wave*1024)

    // A fragments: A[m=16t+nl][k=kb*32+quad*8+j], kept in registers for all 16 chunks
    bf16x8 afrag[2][8];
#pragma unroll
    for (int rt = 0; rt < 2; ++rt) {
        const float* rp = ref + ((size_t)b * Ss + rowbase + rt * 16 + nl) * Hh;
#pragma unroll
        for (int kb = 0; kb < 8; ++kb)
            afrag[rt][kb] = ld_bf8_f32(rp + kb * 32 + quad * 8);
    }

    // stage chunk 0
    stage16(Wbf + soff0, &Wlds[0][dbase0]);
    stage16(Wbf + soff1, &Wlds[0][dbase1]);
    __syncthreads();

    float sc[2][4] = {{0.f, 0.f, 0.f, 0.f}, {0.f, 0.f, 0.f, 0.f}};

    for (int nc = 0; nc < 16; ++nc) {
        const int cur = nc & 1;
        if (nc < 15) {  // prefetch next chunk into the other buffer (async)
            const short* gsrc = Wbf + ((nc + 1) << 12);
            stage16(gsrc + soff0, &Wlds[1 - cur][dbase0]);
            stage16(gsrc + soff1, &Wlds[1 - cur][dbase1]);
        }
        const int n = nc * 16 + nl;
        const float qb = qbias[b * Hh + n];
        const float vv = vvec[n];
        bf16x8 bfrag[8];
#pragma unroll
        for (int kb = 0; kb < 8; ++kb)
            bfrag[kb] = *(const bf16x8*)&Wlds[cur][kb * 512 + lane * 8];
#pragma unroll
        for (int rt = 0; rt < 2; ++rt) {
            f32x4 c = {0.f, 0.f, 0.f, 0.f};
#pragma unroll
            for (int kb = 0; kb < 8; ++kb)
                c = __builtin_amdgcn_mfma_f32_16x16x32_bf16(afrag[rt][kb], bfrag[kb], c, 0, 0, 0);
            // C/D: col = lane&15 (= n-lane), row = quad*4 + r
#pragma unroll
            for (int r = 0; r < 4; ++r)
                sc[rt][r] += fast_tanh(c[r] + qb) * vv;
        }
        __syncthreads();  // drains prefetch vmcnt + guards buffer swap
    }

    // reduce over the 16 n-lanes within each quad
#pragma unroll
    for (int rt = 0; rt < 2; ++rt)
#pragma unroll
        for (int r = 0; r < 4; ++r) {
            float v = sc[rt][r];
            v += __shfl_xor(v, 1, 64);
            v += __shfl_xor(v, 2, 64);
            v += __shfl_xor(v, 4, 64);
            v += __shfl_xor(v, 8, 64);
            sc[rt][r] = v;
        }

    if (nl == 0) {
#pragma unroll
        for (int rt = 0; rt < 2; ++rt)
#pragma unroll
            for (int r = 0; r < 4; ++r) {
                int m = rowbase + rt * 16 + quad * 4 + r;
                float v = sc[rt][r];
                if (MASKED) v -= (float)mask[b * Ss + m] * NEGF;
                out[(size_t)b * Ss + m] = v;
            }
    }
}

// ---------------- Softmax over S per batch (mask applied) -> att ----------------
__global__ __launch_bounds__(1024) void softmax_kernel(const float* __restrict__ scores,
                                                       const int* __restrict__ mask,
                                                       float* __restrict__ att) {
    int b = blockIdx.x, t = threadIdx.x;
    __shared__ float red[16];
    int idx = b * Ss + t;
    float x = scores[idx] - (float)mask[idx] * NEGF;

    float m = x;
#pragma unroll
    for (int o = 1; o < 64; o <<= 1) m = fmaxf(m, __shfl_xor(m, o, 64));
    if ((t & 63) == 0) red[t >> 6] = m;
    __syncthreads();
    float M = red[0];
#pragma unroll
    for (int j = 1; j < 16; ++j) M = fmaxf(M, red[j]);
    __syncthreads();

    float e = __expf(x - M);
    float s = e;
#pragma unroll
    for (int o = 1; o < 64; o <<= 1) s += __shfl_xor(s, o, 64);
    if ((t & 63) == 0) red[t >> 6] = s;
    __syncthreads();
    float S = 0.f;
#pragma unroll
    for (int j = 0; j < 16; ++j) S += red[j];

    att[idx] = e * __builtin_amdgcn_rcpf(S);
}

// ---------------- Glimpse partial: gpart[b,q,d] = sum_{s in 1/8th q} att[b,s]*ref[b,s,d]
__global__ __launch_bounds__(256) void glimpse_part(const float* __restrict__ ref,
                                                    const float* __restrict__ att,
                                                    float* __restrict__ gpart) {
    int b = blockIdx.x, q = blockIdx.y, d = threadIdx.x;
    const float* rp = ref + ((size_t)b * Ss + q * 128) * Hh + d;
    const float* ap = att + b * Ss + q * 128;
    float acc = 0.f;
#pragma unroll 8
    for (int s = 0; s < 128; ++s) acc += ap[s] * rp[(size_t)s * Hh];
    gpart[(b * 8 + q) * Hh + d] = acc;
}

// ---------------- qbias_p[b,h] = sum_d glimpse[b,d]*wqp[h,d] + bp[h] ------------
__global__ __launch_bounds__(256) void qbias_p_kernel(const float* __restrict__ gpart,
                                                      const float* __restrict__ query,
                                                      const float* __restrict__ wqp,
                                                      const float* __restrict__ bp,
                                                      float* __restrict__ out) {
    int b = blockIdx.x, t = threadIdx.x;
    __shared__ __align__(16) float gl[Hh];
    float g = query[b * Hh + t];
#pragma unroll
    for (int q = 0; q < 8; ++q) g += gpart[(b * 8 + q) * Hh + t];
    gl[t] = g;
    __syncthreads();
    const float4* wr = (const float4*)(wqp + t * Hh);
    const float4* gp = (const float4*)gl;
    float acc = 0.f;
#pragma unroll 8
    for (int i = 0; i < Hh / 4; ++i) {
        float4 w4 = wr[i];
        float4 g4 = gp[i];
        acc += w4.x * g4.x + w4.y * g4.y + w4.z * g4.z + w4.w * g4.w;
    }
    out[b * Hh + t] = acc + bp[t];
}

extern "C" void kernel_launch(void* const* d_in, const int* in_sizes, int n_in,
                              void* d_out, int out_size, void* d_ws, size_t ws_size,
                              hipStream_t stream) {
    const float* ref   = (const float*)d_in[0];
    const float* query = (const float*)d_in[1];
    const int*   mask  = (const int*)d_in[2];
    const float* wg    = (const float*)d_in[3];
    const float* bg    = (const float*)d_in[4];
    const float* wqg   = (const float*)d_in[5];
    const float* vg    = (const float*)d_in[6];
    const float* wp    = (const float*)d_in[7];
    const float* bp    = (const float*)d_in[8];
    const float* wqp   = (const float*)d_in[9];
    const float* vp    = (const float*)d_in[10];
    float* out = (float*)d_out;

    char* ws = (char*)d_ws;
    short* wg_bf    = (short*)(ws + 0);        // 131072 B
    short* wp_bf    = (short*)(ws + 131072);   // 131072 B
    float* qbias_g  = (float*)(ws + 262144);   // 131072 B
    float* qbias_p  = (float*)(ws + 393216);   // 131072 B
    float* scores_g = (float*)(ws + 524288);   // 524288 B
    float* att      = (float*)(ws + 1048576);  // 524288 B
    float* gpart    = (float*)(ws + 1572864);  // 1048576 B (total 2.5 MB)

    convert_w<<<Hh * Hh / 256, 256, 0, stream>>>(wg, wp, wg_bf, wp_bf);
    dot_qb<<<Bb, Hh, 0, stream>>>(query, wqg, bg, qbias_g);
    scores_mfma<0><<<dim3(Bb, Ss / 128), 256, 0, stream>>>(ref, wg_bf, qbias_g, vg, nullptr, scores_g);
    softmax_kernel<<<Bb, Ss, 0, stream>>>(scores_g, mask, att);
    glimpse_part<<<dim3(Bb, 8), 256, 0, stream>>>(ref, att, gpart);
    qbias_p_kernel<<<Bb, Hh, 0, stream>>>(gpart, query, wqp, bp, qbias_p);
    scores_mfma<1><<<dim3(Bb, Ss / 128), 256, 0, stream>>>(ref, wp_bf, qbias_p, vp, mask, out);
}